// Round 3
// baseline (266.334 us; speedup 1.0000x reference)
//
#include <hip/hip_runtime.h>

// ============================================================================
// GPT-2 attention block on gfx950, bf16 MFMA throughout.
//
// R3 changes:
//  - GEMMs: BK=64 (two m97-chunk k-panels per tensor, 32 KB LDS) -> half the
//    barrier rounds, 32 MFMA/wave/round. K=1024 -> 16 rounds.
//  - attn: key axis of the P*V contraction permuted pos=(key&15)*4+(key>>4).
//    V^T is stored pos-permuted by gemm_qkv's epilogue; P's exp2 results pack
//    into bf16x4 ds_write_b64 (8 stores/lane/iter vs 32 scalar). MFMA k-axis
//    runs over pos in both operands -> product unchanged.
// ============================================================================

typedef __bf16 bf16_t;
typedef __bf16 bf16x8 __attribute__((ext_vector_type(8)));
typedef __bf16 bf16x4 __attribute__((ext_vector_type(4)));
typedef float  f32x4  __attribute__((ext_vector_type(4)));

#define DI __device__ __forceinline__

static constexpr int Bq = 4, Sq = 2048, NXq = 1024, NHq = 16, HDq = 64;

DI void gl2lds16(const void* g, void* l) {
#if defined(__has_builtin)
#if __has_builtin(__builtin_amdgcn_global_load_lds)
  __builtin_amdgcn_global_load_lds(
      (const __attribute__((address_space(1))) void*)g,
      (__attribute__((address_space(3))) void*)l, 16, 0, 0);
  return;
#endif
#endif
  *(bf16x8*)l = *(const bf16x8*)g;
}

DI float fast_exp2(float x) {
#if defined(__has_builtin)
#if __has_builtin(__builtin_amdgcn_exp2f)
  return __builtin_amdgcn_exp2f(x);
#else
  return exp2f(x);
#endif
#else
  return exp2f(x);
#endif
}

// ---------------------------------------------------------------------------
// k0: fp32 -> bf16 convert
// ---------------------------------------------------------------------------
__global__ __launch_bounds__(256) void cvt_bf16(const float* __restrict__ in,
                                                bf16_t* __restrict__ out, int n) {
  int i = (blockIdx.x * 256 + threadIdx.x) * 4;
  if (i >= n) return;
  float4 v = *(const float4*)(in + i);
  bf16x4 o;
  o[0] = (bf16_t)v.x; o[1] = (bf16_t)v.y; o[2] = (bf16_t)v.z; o[3] = (bf16_t)v.w;
  *(bf16x4*)(out + i) = o;
}

// ---------------------------------------------------------------------------
// k1: transpose + convert
// ---------------------------------------------------------------------------
__global__ __launch_bounds__(256) void transpose_cvt(const float* __restrict__ in,
                                                     bf16_t* __restrict__ out,
                                                     int R, int C) {
  __shared__ float t[32][33];
  int bx = blockIdx.x * 32, by = blockIdx.y * 32;
  int tx = threadIdx.x, ty = threadIdx.y;
#pragma unroll
  for (int i = 0; i < 32; i += 8)
    t[ty + i][tx] = in[(size_t)(by + ty + i) * C + bx + tx];
  __syncthreads();
#pragma unroll
  for (int i = 0; i < 32; i += 8)
    out[(size_t)(bx + ty + i) * R + by + tx] = (bf16_t)t[tx][ty + i];
}

// ---------------------------------------------------------------------------
// GEMM main loop, BK=64: C[128,128] += A[128,K] * Bt[128,K]^T.
// LDS per tensor: 2 k-panels (k 0..31 / 32..63), each [128 rows][32 k] in
// m97 chunk layout (16-row units of 512 elems). 16 staging units per tensor
// per round; wave w stages units w*4..w*4+3. 32 MFMA/wave/round.
// ---------------------------------------------------------------------------
DI void gemm_main64(const bf16_t* __restrict__ A, const bf16_t* __restrict__ Bt,
                    int K, f32x4 acc[4][4], bf16_t* As, bf16_t* Bs,
                    int lane, int w) {
  const int wy = w >> 1, wx = w & 1;
  const int l15 = lane & 15, quad = lane >> 4;
  const int sr = lane >> 2, sk = (lane & 3) * 8;
  for (int kt = 0; kt < K; kt += 64) {
    __syncthreads();
#pragma unroll
    for (int i = 0; i < 4; ++i) {
      int u = w * 4 + i;           // 0..15
      int p = u >> 3, g = u & 7;   // k-panel, 16-row group
      int row = g * 16 + sr;
      int ko = kt + p * 32 + sk;
      gl2lds16(A + (size_t)row * K + ko, As + u * 512 + lane * 8);
      gl2lds16(Bt + (size_t)row * K + ko, Bs + u * 512 + lane * 8);
    }
    __syncthreads();
#pragma unroll
    for (int ks = 0; ks < 2; ++ks) {
      bf16x8 af[4], bfr[4];
#pragma unroll
      for (int mi = 0; mi < 4; ++mi)
        af[mi] = *(const bf16x8*)(As + ks * 4096 + (wy * 4 + mi) * 512 + l15 * 32 + quad * 8);
#pragma unroll
      for (int ni = 0; ni < 4; ++ni)
        bfr[ni] = *(const bf16x8*)(Bs + ks * 4096 + (wx * 4 + ni) * 512 + l15 * 32 + quad * 8);
#pragma unroll
      for (int mi = 0; mi < 4; ++mi)
#pragma unroll
        for (int ni = 0; ni < 4; ++ni)
          acc[mi][ni] = __builtin_amdgcn_mfma_f32_16x16x32_bf16(
              af[mi], bfr[ni], acc[mi][ni], 0, 0, 0);
    }
  }
}

// ---------------------------------------------------------------------------
// k2: QKV GEMM. Epilogue: q scaled by 0.125*log2e -> [b,h,s,d];
// k -> [b,h,s,d]; V -> v^T[b,h,d,pos] with pos = 64-block-local
// (key&15)*4 + (key>>4) permutation (see attn P*V contract).
// ---------------------------------------------------------------------------
__global__ __launch_bounds__(256) void gemm_qkv(
    const bf16_t* __restrict__ X, const bf16_t* __restrict__ Wt,
    const float* __restrict__ bias, bf16_t* __restrict__ qw,
    bf16_t* __restrict__ kw, bf16_t* __restrict__ vtw) {
  __shared__ __align__(16) bf16_t As[128 * 64];
  __shared__ __align__(16) bf16_t Bs[128 * 64];
  const int tid = threadIdx.x, lane = tid & 63, w = tid >> 6;
  const int m0 = blockIdx.y * 128, n0 = blockIdx.x * 128;
  f32x4 acc[4][4];
#pragma unroll
  for (int mi = 0; mi < 4; ++mi)
#pragma unroll
    for (int ni = 0; ni < 4; ++ni) acc[mi][ni] = (f32x4){0.f, 0.f, 0.f, 0.f};
  gemm_main64(X + (size_t)m0 * NXq, Wt + (size_t)n0 * NXq, NXq, acc, As, Bs, lane, w);

  const int wy = w >> 1, wx = w & 1, l15 = lane & 15, quad = lane >> 4;
  const float qscale = 0.125f * 1.44269504088896340736f;
#pragma unroll
  for (int mi = 0; mi < 4; ++mi) {
    int rowb = m0 + wy * 64 + mi * 16 + quad * 4;
    int bb = rowb >> 11, sl = rowb & 2047;
#pragma unroll
    for (int ni = 0; ni < 4; ++ni) {
      int col = n0 + wx * 64 + ni * 16 + l15;
      float bv = bias[col];
      f32x4 v = acc[mi][ni];
      int sec = col >> 10;
      int c = col & 1023;
      int h = c >> 6, d = c & 63;
      if (sec == 0) {
#pragma unroll
        for (int r = 0; r < 4; ++r)
          qw[(((size_t)bb * NHq + h) * Sq + sl + r) * HDq + d] =
              (bf16_t)((v[r] + bv) * qscale);
      } else if (sec == 1) {
#pragma unroll
        for (int r = 0; r < 4; ++r)
          kw[(((size_t)bb * NHq + h) * Sq + sl + r) * HDq + d] = (bf16_t)(v[r] + bv);
      } else {
        // pos-permuted V^T: key = sl64 + r, pos = (key&15)*4 + (key>>4)
        int sl64 = sl & 63;                       // 4-aligned
        int pos0 = (sl & ~63) + ((sl64 & 15) << 2) + (sl64 >> 4);
        bf16_t* vb = vtw + (((size_t)bb * NHq + h) * HDq + d) * Sq + pos0;
#pragma unroll
        for (int r = 0; r < 4; ++r) vb[4 * r] = (bf16_t)(v[r] + bv);
      }
    }
  }
}

// ---------------------------------------------------------------------------
// k3: flash attention, causal. BQ=128, BK=64. Wave w owns q-rows [w*32,+32).
// No-max exp2 softmax (scores bounded); per-lane partial row sums.
// P stored in pos-space: lane's 4 values (keys l15+16*nt) -> contiguous
// positions l15*4+nt -> one bf16x4 ds_write_b64 per (mi,r). V^T already
// pos-permuted in global, so PV's k-axis is pos for both operands.
// ---------------------------------------------------------------------------
__global__ __launch_bounds__(256, 4) void attn_fwd(
    const bf16_t* __restrict__ qw, const bf16_t* __restrict__ kw,
    const bf16_t* __restrict__ vtw, bf16_t* __restrict__ aw) {
  __shared__ __align__(16) bf16_t Ks[4096], Vs[4096];
  __shared__ __align__(16) bf16_t Ps[4][32 * 72];
  const int tid = threadIdx.x, lane = tid & 63, w = tid >> 6;
  const int l15 = lane & 15, quad = lane >> 4;

  // block swizzle: XCD locality (8 heads/XCD) + balanced CU packing
  const int id = blockIdx.x;
  const int bh = ((id & 7) << 3) | ((id >> 3) & 7);
  const int k4 = (id >> 6) & 3, quarter = id >> 8;
  int qtile;
  if (quarter == 0)      qtile = 15 - k4;
  else if (quarter == 1) qtile = 8 + k4;
  else if (quarter == 2) qtile = 7 - k4;
  else                   qtile = k4;
  const int b = bh >> 4, h = bh & 15;

  const bf16_t* Qg = qw + ((size_t)bh * Sq + qtile * 128) * HDq;
  const bf16_t* Kg = kw + (size_t)bh * Sq * HDq;
  const bf16_t* Vg = vtw + (size_t)bh * HDq * Sq;

  bf16x8 qf[2][2];
#pragma unroll
  for (int mi = 0; mi < 2; ++mi)
#pragma unroll
    for (int ks = 0; ks < 2; ++ks)
      qf[mi][ks] = *(const bf16x8*)(
          Qg + (size_t)((w * 2 + mi) * 16 + l15) * HDq + ks * 32 + quad * 8);

  f32x4 o[2][4];
  float lsum[2][4];
#pragma unroll
  for (int mi = 0; mi < 2; ++mi) {
#pragma unroll
    for (int dt = 0; dt < 4; ++dt) o[mi][dt] = (f32x4){0.f, 0.f, 0.f, 0.f};
#pragma unroll
    for (int r = 0; r < 4; ++r) lsum[mi][r] = 0.f;
  }

  bf16_t* Pw = &Ps[w][0];
  const int jmax = 2 * qtile + 2;
  for (int jt = 0; jt < jmax; ++jt) {
    __syncthreads();
#pragma unroll
    for (int i = 0; i < 2; ++i) {
      int u = w * 2 + i, p = u >> 2, g = u & 3;
      gl2lds16(Kg + (size_t)(jt * 64 + g * 16 + (lane >> 2)) * HDq + p * 32 + (lane & 3) * 8,
               Ks + u * 512 + lane * 8);
      gl2lds16(Vg + (size_t)(g * 16 + (lane >> 2)) * Sq + jt * 64 + p * 32 + (lane & 3) * 8,
               Vs + u * 512 + lane * 8);
    }
    __syncthreads();

    // ---- S = Q K^T (exp2 domain) ----
    f32x4 sc[2][4];
#pragma unroll
    for (int mi = 0; mi < 2; ++mi)
#pragma unroll
      for (int nt = 0; nt < 4; ++nt) sc[mi][nt] = (f32x4){0.f, 0.f, 0.f, 0.f};
#pragma unroll
    for (int ks = 0; ks < 2; ++ks)
#pragma unroll
      for (int nt = 0; nt < 4; ++nt) {
        bf16x8 kf = *(const bf16x8*)(Ks + ks * 2048 + nt * 512 + (l15 * 4 + quad) * 8);
        sc[0][nt] = __builtin_amdgcn_mfma_f32_16x16x32_bf16(qf[0][ks], kf, sc[0][nt], 0, 0, 0);
        sc[1][nt] = __builtin_amdgcn_mfma_f32_16x16x32_bf16(qf[1][ks], kf, sc[1][nt], 0, 0, 0);
      }

    if (jt >= 2 * qtile) {  // causal mask on diagonal-overlapping tiles
#pragma unroll
      for (int mi = 0; mi < 2; ++mi) {
        int qrow = qtile * 128 + (w * 2 + mi) * 16 + quad * 4;
#pragma unroll
        for (int nt = 0; nt < 4; ++nt) {
          int key = jt * 64 + nt * 16 + l15;
#pragma unroll
          for (int r = 0; r < 4; ++r)
            if (key > qrow + r) sc[mi][nt][r] = -1e30f;
        }
      }
    }

    // ---- p = exp2(s); pack 4 keys (pos-contig) -> one b64 store ----
#pragma unroll
    for (int mi = 0; mi < 2; ++mi)
#pragma unroll
      for (int r = 0; r < 4; ++r) {
        bf16x4 pk;
#pragma unroll
        for (int nt = 0; nt < 4; ++nt) {
          float p = fast_exp2(sc[mi][nt][r]);
          lsum[mi][r] += p;
          pk[nt] = (bf16_t)p;
        }
        *(bf16x4*)(Pw + (mi * 16 + quad * 4 + r) * 72 + l15 * 4) = pk;
      }
    // no barrier: Ps[w] wave-private, DS pipe in-order per wave

    // ---- O += P V (k-axis = pos for both operands) ----
#pragma unroll
    for (int kk = 0; kk < 2; ++kk) {
      bf16x8 ap0 = *(const bf16x8*)(Pw + (size_t)l15 * 72 + kk * 32 + quad * 8);
      bf16x8 ap1 = *(const bf16x8*)(Pw + (size_t)(16 + l15) * 72 + kk * 32 + quad * 8);
#pragma unroll
      for (int dt = 0; dt < 4; ++dt) {
        bf16x8 bv = *(const bf16x8*)(Vs + kk * 2048 + dt * 512 + (l15 * 4 + quad) * 8);
        o[0][dt] = __builtin_amdgcn_mfma_f32_16x16x32_bf16(ap0, bv, o[0][dt], 0, 0, 0);
        o[1][dt] = __builtin_amdgcn_mfma_f32_16x16x32_bf16(ap1, bv, o[1][dt], 0, 0, 0);
      }
    }
  }

  float linv[2][4];
#pragma unroll
  for (int mi = 0; mi < 2; ++mi)
#pragma unroll
    for (int r = 0; r < 4; ++r) {
      float s = lsum[mi][r];
#pragma unroll
      for (int off = 8; off > 0; off >>= 1) s += __shfl_xor(s, off);
      linv[mi][r] = 1.f / s;
    }

#pragma unroll
  for (int mi = 0; mi < 2; ++mi) {
    int s0 = qtile * 128 + (w * 2 + mi) * 16 + quad * 4;
#pragma unroll
    for (int dt = 0; dt < 4; ++dt) {
      int col = h * 64 + dt * 16 + l15;
#pragma unroll
      for (int r = 0; r < 4; ++r)
        aw[((size_t)b * Sq + s0 + r) * NXq + col] = (bf16_t)(o[mi][dt][r] * linv[mi][r]);
    }
  }
}

// ---------------------------------------------------------------------------
// k4: output projection GEMM -> fp32 out + bias
// ---------------------------------------------------------------------------
__global__ __launch_bounds__(256) void gemm_proj(
    const bf16_t* __restrict__ Aa, const bf16_t* __restrict__ Wt,
    const float* __restrict__ bias, float* __restrict__ out) {
  __shared__ __align__(16) bf16_t As[128 * 64];
  __shared__ __align__(16) bf16_t Bs[128 * 64];
  const int tid = threadIdx.x, lane = tid & 63, w = tid >> 6;
  const int m0 = blockIdx.y * 128, n0 = blockIdx.x * 128;
  f32x4 acc[4][4];
#pragma unroll
  for (int mi = 0; mi < 4; ++mi)
#pragma unroll
    for (int ni = 0; ni < 4; ++ni) acc[mi][ni] = (f32x4){0.f, 0.f, 0.f, 0.f};
  gemm_main64(Aa + (size_t)m0 * NXq, Wt + (size_t)n0 * NXq, NXq, acc, As, Bs, lane, w);

  const int wy = w >> 1, wx = w & 1, l15 = lane & 15, quad = lane >> 4;
#pragma unroll
  for (int mi = 0; mi < 4; ++mi) {
    int rowb = m0 + wy * 64 + mi * 16 + quad * 4;
#pragma unroll
    for (int ni = 0; ni < 4; ++ni) {
      int col = n0 + wx * 64 + ni * 16 + l15;
      float bv = bias[col];
#pragma unroll
      for (int r = 0; r < 4; ++r)
        out[(size_t)(rowb + r) * NXq + col] = acc[mi][ni][r] + bv;
    }
  }
}

// ---------------------------------------------------------------------------
// launch
// ---------------------------------------------------------------------------
extern "C" void kernel_launch(void* const* d_in, const int* in_sizes, int n_in,
                              void* d_out, int out_size, void* d_ws, size_t ws_size,
                              hipStream_t stream) {
  const float* hidden   = (const float*)d_in[0];
  const float* c_attn_w = (const float*)d_in[1];
  const float* c_attn_b = (const float*)d_in[2];
  const float* c_proj_w = (const float*)d_in[3];
  const float* c_proj_b = (const float*)d_in[4];
  float* out = (float*)d_out;

  char* ws = (char*)d_ws;
  const size_t szX   = (size_t)8192 * 1024 * 2;
  const size_t szW1  = (size_t)3072 * 1024 * 2;
  const size_t szW2  = (size_t)1024 * 1024 * 2;
  const size_t szQKV = (size_t)Bq * NHq * Sq * HDq * 2;
  bf16_t* Xb  = (bf16_t*)(ws);
  bf16_t* Wt1 = (bf16_t*)(ws + szX);
  bf16_t* Wt2 = (bf16_t*)(ws + szX + szW1);
  bf16_t* qwp = (bf16_t*)(ws + szX + szW1 + szW2);
  bf16_t* kwp = (bf16_t*)(ws + szX + szW1 + szW2 + szQKV);
  bf16_t* vtp = (bf16_t*)(ws + szX + szW1 + szW2 + 2 * szQKV);
  bf16_t* awp = (bf16_t*)(ws + szX + szW1 + szW2 + 3 * szQKV);
  if (ws_size < szX + szW1 + szW2 + 4 * szQKV) return;

  cvt_bf16<<<dim3((8192 * 1024) / (256 * 4)), dim3(256), 0, stream>>>(
      hidden, Xb, 8192 * 1024);
  transpose_cvt<<<dim3(3072 / 32, 1024 / 32), dim3(32, 8), 0, stream>>>(
      c_attn_w, Wt1, 1024, 3072);
  transpose_cvt<<<dim3(1024 / 32, 1024 / 32), dim3(32, 8), 0, stream>>>(
      c_proj_w, Wt2, 1024, 1024);
  gemm_qkv<<<dim3(3072 / 128, 8192 / 128), dim3(256), 0, stream>>>(
      Xb, Wt1, c_attn_b, qwp, kwp, vtp);
  attn_fwd<<<dim3(1024), dim3(256), 0, stream>>>(qwp, kwp, vtp, awp);
  gemm_proj<<<dim3(1024 / 128, 8192 / 128), dim3(256), 0, stream>>>(
      awp, Wt2, c_proj_b, out);
}

// Round 4
// 256.208 us; speedup vs baseline: 1.0395x; 1.0395x over previous
//
#include <hip/hip_runtime.h>

// ============================================================================
// GPT-2 attention block on gfx950, bf16 MFMA throughout.
//
// R4: revert R3's BK=64 (occupancy cliff: MfmaUtil 28->21, Occ 29->17.5 —
// m132 pattern). Back to R2's BK=32 m97-structure GEMMs + R2 attn.
// New in R4: gemm_qkv epilogue for Q/K blocks goes through an LDS transpose
// (64x132-stride tile, conflict-free) -> bf16x8 16B global stores:
// 8 vector stores/lane instead of 64 scalar 2B stores.
// ============================================================================

typedef __bf16 bf16_t;
typedef __bf16 bf16x8 __attribute__((ext_vector_type(8)));
typedef __bf16 bf16x4 __attribute__((ext_vector_type(4)));
typedef float  f32x4  __attribute__((ext_vector_type(4)));

#define DI __device__ __forceinline__

static constexpr int Bq = 4, Sq = 2048, NXq = 1024, NHq = 16, HDq = 64;

DI void gl2lds16(const void* g, void* l) {
#if defined(__has_builtin)
#if __has_builtin(__builtin_amdgcn_global_load_lds)
  __builtin_amdgcn_global_load_lds(
      (const __attribute__((address_space(1))) void*)g,
      (__attribute__((address_space(3))) void*)l, 16, 0, 0);
  return;
#endif
#endif
  *(bf16x8*)l = *(const bf16x8*)g;
}

DI float fast_exp2(float x) {
#if defined(__has_builtin)
#if __has_builtin(__builtin_amdgcn_exp2f)
  return __builtin_amdgcn_exp2f(x);
#else
  return exp2f(x);
#endif
#else
  return exp2f(x);
#endif
}

// ---------------------------------------------------------------------------
// k0: fp32 -> bf16 convert
// ---------------------------------------------------------------------------
__global__ __launch_bounds__(256) void cvt_bf16(const float* __restrict__ in,
                                                bf16_t* __restrict__ out, int n) {
  int i = (blockIdx.x * 256 + threadIdx.x) * 4;
  if (i >= n) return;
  float4 v = *(const float4*)(in + i);
  bf16x4 o;
  o[0] = (bf16_t)v.x; o[1] = (bf16_t)v.y; o[2] = (bf16_t)v.z; o[3] = (bf16_t)v.w;
  *(bf16x4*)(out + i) = o;
}

// ---------------------------------------------------------------------------
// k1: transpose + convert
// ---------------------------------------------------------------------------
__global__ __launch_bounds__(256) void transpose_cvt(const float* __restrict__ in,
                                                     bf16_t* __restrict__ out,
                                                     int R, int C) {
  __shared__ float t[32][33];
  int bx = blockIdx.x * 32, by = blockIdx.y * 32;
  int tx = threadIdx.x, ty = threadIdx.y;
#pragma unroll
  for (int i = 0; i < 32; i += 8)
    t[ty + i][tx] = in[(size_t)(by + ty + i) * C + bx + tx];
  __syncthreads();
#pragma unroll
  for (int i = 0; i < 32; i += 8)
    out[(size_t)(bx + ty + i) * R + by + tx] = (bf16_t)t[tx][ty + i];
}

// ---------------------------------------------------------------------------
// GEMM main loop (m97 structure, BK=32 — the R2 config):
// C[128,128] += A[128,K] * Bt[128,K]^T, LDS [128 rows][32 k] chunk layout.
// ---------------------------------------------------------------------------
DI void gemm_main(const bf16_t* __restrict__ A, const bf16_t* __restrict__ Bt,
                  int K, f32x4 acc[4][4], bf16_t* As, bf16_t* Bs,
                  int lane, int w) {
  const int wy = w >> 1, wx = w & 1;
  const int l15 = lane & 15, quad = lane >> 4;
  for (int kt = 0; kt < K; kt += 32) {
    __syncthreads();
#pragma unroll
    for (int i = 0; i < 2; ++i) {
      int g = w * 2 + i;
      int row = g * 16 + (lane >> 2);
      int ko = kt + (lane & 3) * 8;
      gl2lds16(A + (size_t)row * K + ko, As + g * 512 + lane * 8);
      gl2lds16(Bt + (size_t)row * K + ko, Bs + g * 512 + lane * 8);
    }
    __syncthreads();
    bf16x8 af[4], bfr[4];
#pragma unroll
    for (int mi = 0; mi < 4; ++mi)
      af[mi] = *(const bf16x8*)(As + (wy * 64 + mi * 16 + l15) * 32 + quad * 8);
#pragma unroll
    for (int ni = 0; ni < 4; ++ni)
      bfr[ni] = *(const bf16x8*)(Bs + (wx * 64 + ni * 16 + l15) * 32 + quad * 8);
#pragma unroll
    for (int mi = 0; mi < 4; ++mi)
#pragma unroll
      for (int ni = 0; ni < 4; ++ni)
        acc[mi][ni] = __builtin_amdgcn_mfma_f32_16x16x32_bf16(
            af[mi], bfr[ni], acc[mi][ni], 0, 0, 0);
  }
}

// ---------------------------------------------------------------------------
// k2: QKV GEMM. Q/K blocks: LDS-transposed epilogue -> bf16x8 stores.
// V blocks: direct bf16x4 token-contiguous stores into v^T[b,h,d,s].
// Q pre-scaled by 0.125*log2e for exp2-domain softmax.
// ---------------------------------------------------------------------------
__global__ __launch_bounds__(256) void gemm_qkv(
    const bf16_t* __restrict__ X, const bf16_t* __restrict__ Wt,
    const float* __restrict__ bias, bf16_t* __restrict__ qw,
    bf16_t* __restrict__ kw, bf16_t* __restrict__ vtw) {
  // staging: As = smem[0..4095], Bs = smem[4096..8191] (16 KB);
  // epilogue reuses smem as T[64][132] bf16 (16.9 KB total block LDS).
  __shared__ __align__(16) bf16_t smem[64 * 132];
  bf16_t* As = smem;
  bf16_t* Bs = smem + 4096;
  const int tid = threadIdx.x, lane = tid & 63, w = tid >> 6;
  const int m0 = blockIdx.y * 128, n0 = blockIdx.x * 128;
  f32x4 acc[4][4];
#pragma unroll
  for (int mi = 0; mi < 4; ++mi)
#pragma unroll
    for (int ni = 0; ni < 4; ++ni) acc[mi][ni] = (f32x4){0.f, 0.f, 0.f, 0.f};
  gemm_main(X + (size_t)m0 * NXq, Wt + (size_t)n0 * NXq, NXq, acc, As, Bs, lane, w);

  const int wy = w >> 1, wx = w & 1, l15 = lane & 15, quad = lane >> 4;
  const float qscale = 0.125f * 1.44269504088896340736f;

  if (n0 < 2048) {
    // ---- Q or K: transpose through LDS, then 16B stores ----
    const float scale = (n0 < 1024) ? qscale : 1.f;
    bf16_t* outp = (n0 < 1024) ? qw : kw;
    const int nb = n0 & 1023;
    for (int half = 0; half < 2; ++half) {
      __syncthreads();  // staging/prev-half reads done before overwrite
      if (wy == half) {
#pragma unroll
        for (int mi = 0; mi < 4; ++mi) {
          int lr = mi * 16 + quad * 4;
#pragma unroll
          for (int ni = 0; ni < 4; ++ni) {
            int lc = wx * 64 + ni * 16 + l15;
            float bv = bias[n0 + lc];
            f32x4 v = acc[mi][ni];
#pragma unroll
            for (int r = 0; r < 4; ++r)
              smem[(lr + r) * 132 + lc] = (bf16_t)((v[r] + bv) * scale);
          }
        }
      }
      __syncthreads();
      int row = tid >> 2, cb = (tid & 3) * 32;
      int gtok = m0 + half * 64 + row;
      int bb = gtok >> 11, sl = gtok & 2047;
#pragma unroll
      for (int c = 0; c < 4; ++c) {
        int col = cb + c * 8;
        bf16x8 d8 = *(const bf16x8*)(smem + row * 132 + col);
        int cc = nb + col;
        int hh = cc >> 6, dd = cc & 63;
        *(bf16x8*)(outp + (((size_t)bb * NHq + hh) * Sq + sl) * HDq + dd) = d8;
      }
    }
  } else {
    // ---- V: v^T[b,h,d,s], 4 consecutive tokens per fragment -> bf16x4 ----
#pragma unroll
    for (int mi = 0; mi < 4; ++mi) {
      int rowb = m0 + wy * 64 + mi * 16 + quad * 4;
      int bb = rowb >> 11, sl = rowb & 2047;
#pragma unroll
      for (int ni = 0; ni < 4; ++ni) {
        int col = n0 + wx * 64 + ni * 16 + l15;
        float bv = bias[col];
        f32x4 v = acc[mi][ni];
        int c = col & 1023;
        int h = c >> 6, d = c & 63;
        bf16x4 t;
#pragma unroll
        for (int r = 0; r < 4; ++r) t[r] = (bf16_t)(v[r] + bv);
        *(bf16x4*)(vtw + (((size_t)bb * NHq + h) * HDq + d) * Sq + sl) = t;
      }
    }
  }
}

// ---------------------------------------------------------------------------
// k3: flash attention, causal (R2 version). BQ=128, BK=64, 1024 blocks.
// No-max exp2 softmax; per-lane partial row sums; P wave-private in LDS.
// ---------------------------------------------------------------------------
__global__ __launch_bounds__(256, 4) void attn_fwd(
    const bf16_t* __restrict__ qw, const bf16_t* __restrict__ kw,
    const bf16_t* __restrict__ vtw, bf16_t* __restrict__ aw) {
  __shared__ __align__(16) bf16_t Ks[4096], Vs[4096];
  __shared__ __align__(16) bf16_t Ps[4][32 * 72];
  const int tid = threadIdx.x, lane = tid & 63, w = tid >> 6;
  const int l15 = lane & 15, quad = lane >> 4;

  const int id = blockIdx.x;
  const int bh = ((id & 7) << 3) | ((id >> 3) & 7);
  const int k4 = (id >> 6) & 3, quarter = id >> 8;
  int qtile;
  if (quarter == 0)      qtile = 15 - k4;
  else if (quarter == 1) qtile = 8 + k4;
  else if (quarter == 2) qtile = 7 - k4;
  else                   qtile = k4;
  const int b = bh >> 4, h = bh & 15;

  const bf16_t* Qg = qw + ((size_t)bh * Sq + qtile * 128) * HDq;
  const bf16_t* Kg = kw + (size_t)bh * Sq * HDq;
  const bf16_t* Vg = vtw + (size_t)bh * HDq * Sq;

  bf16x8 qf[2][2];
#pragma unroll
  for (int mi = 0; mi < 2; ++mi)
#pragma unroll
    for (int ks = 0; ks < 2; ++ks)
      qf[mi][ks] = *(const bf16x8*)(
          Qg + (size_t)((w * 2 + mi) * 16 + l15) * HDq + ks * 32 + quad * 8);

  f32x4 o[2][4];
  float lsum[2][4];
#pragma unroll
  for (int mi = 0; mi < 2; ++mi) {
#pragma unroll
    for (int dt = 0; dt < 4; ++dt) o[mi][dt] = (f32x4){0.f, 0.f, 0.f, 0.f};
#pragma unroll
    for (int r = 0; r < 4; ++r) lsum[mi][r] = 0.f;
  }

  bf16_t* Pw = &Ps[w][0];
  const int jmax = 2 * qtile + 2;
  for (int jt = 0; jt < jmax; ++jt) {
    __syncthreads();
#pragma unroll
    for (int i = 0; i < 2; ++i) {
      int u = w * 2 + i, p = u >> 2, g = u & 3;
      gl2lds16(Kg + (size_t)(jt * 64 + g * 16 + (lane >> 2)) * HDq + p * 32 + (lane & 3) * 8,
               Ks + u * 512 + lane * 8);
      gl2lds16(Vg + (size_t)(g * 16 + (lane >> 2)) * Sq + jt * 64 + p * 32 + (lane & 3) * 8,
               Vs + u * 512 + lane * 8);
    }
    __syncthreads();

    f32x4 sc[2][4];
#pragma unroll
    for (int mi = 0; mi < 2; ++mi)
#pragma unroll
      for (int nt = 0; nt < 4; ++nt) sc[mi][nt] = (f32x4){0.f, 0.f, 0.f, 0.f};
#pragma unroll
    for (int ks = 0; ks < 2; ++ks)
#pragma unroll
      for (int nt = 0; nt < 4; ++nt) {
        bf16x8 kf = *(const bf16x8*)(Ks + ks * 2048 + nt * 512 + (l15 * 4 + quad) * 8);
        sc[0][nt] = __builtin_amdgcn_mfma_f32_16x16x32_bf16(qf[0][ks], kf, sc[0][nt], 0, 0, 0);
        sc[1][nt] = __builtin_amdgcn_mfma_f32_16x16x32_bf16(qf[1][ks], kf, sc[1][nt], 0, 0, 0);
      }

    if (jt >= 2 * qtile) {
#pragma unroll
      for (int mi = 0; mi < 2; ++mi) {
        int qrow = qtile * 128 + (w * 2 + mi) * 16 + quad * 4;
#pragma unroll
        for (int nt = 0; nt < 4; ++nt) {
          int key = jt * 64 + nt * 16 + l15;
#pragma unroll
          for (int r = 0; r < 4; ++r)
            if (key > qrow + r) sc[mi][nt][r] = -1e30f;
        }
      }
    }

#pragma unroll
    for (int mi = 0; mi < 2; ++mi)
#pragma unroll
      for (int nt = 0; nt < 4; ++nt)
#pragma unroll
        for (int r = 0; r < 4; ++r) {
          float p = fast_exp2(sc[mi][nt][r]);
          lsum[mi][r] += p;
          Pw[(mi * 16 + quad * 4 + r) * 72 + nt * 16 + l15] = (bf16_t)p;
        }
    // no barrier: Ps[w] wave-private, DS pipe in-order per wave

#pragma unroll
    for (int kk = 0; kk < 2; ++kk) {
      bf16x8 ap0 = *(const bf16x8*)(Pw + (size_t)l15 * 72 + kk * 32 + quad * 8);
      bf16x8 ap1 = *(const bf16x8*)(Pw + (size_t)(16 + l15) * 72 + kk * 32 + quad * 8);
#pragma unroll
      for (int dt = 0; dt < 4; ++dt) {
        bf16x8 bv = *(const bf16x8*)(Vs + kk * 2048 + dt * 512 + (l15 * 4 + quad) * 8);
        o[0][dt] = __builtin_amdgcn_mfma_f32_16x16x32_bf16(ap0, bv, o[0][dt], 0, 0, 0);
        o[1][dt] = __builtin_amdgcn_mfma_f32_16x16x32_bf16(ap1, bv, o[1][dt], 0, 0, 0);
      }
    }
  }

  float linv[2][4];
#pragma unroll
  for (int mi = 0; mi < 2; ++mi)
#pragma unroll
    for (int r = 0; r < 4; ++r) {
      float s = lsum[mi][r];
#pragma unroll
      for (int off = 8; off > 0; off >>= 1) s += __shfl_xor(s, off);
      linv[mi][r] = 1.f / s;
    }

#pragma unroll
  for (int mi = 0; mi < 2; ++mi) {
    int s0 = qtile * 128 + (w * 2 + mi) * 16 + quad * 4;
#pragma unroll
    for (int dt = 0; dt < 4; ++dt) {
      int col = h * 64 + dt * 16 + l15;
#pragma unroll
      for (int r = 0; r < 4; ++r)
        aw[((size_t)b * Sq + s0 + r) * NXq + col] = (bf16_t)(o[mi][dt][r] * linv[mi][r]);
    }
  }
}

// ---------------------------------------------------------------------------
// k4: output projection GEMM -> fp32 out + bias (R2 version)
// ---------------------------------------------------------------------------
__global__ __launch_bounds__(256) void gemm_proj(
    const bf16_t* __restrict__ Aa, const bf16_t* __restrict__ Wt,
    const float* __restrict__ bias, float* __restrict__ out) {
  __shared__ __align__(16) bf16_t As[128 * 32];
  __shared__ __align__(16) bf16_t Bs[128 * 32];
  const int tid = threadIdx.x, lane = tid & 63, w = tid >> 6;
  const int m0 = blockIdx.y * 128, n0 = blockIdx.x * 128;
  f32x4 acc[4][4];
#pragma unroll
  for (int mi = 0; mi < 4; ++mi)
#pragma unroll
    for (int ni = 0; ni < 4; ++ni) acc[mi][ni] = (f32x4){0.f, 0.f, 0.f, 0.f};
  gemm_main(Aa + (size_t)m0 * NXq, Wt + (size_t)n0 * NXq, NXq, acc, As, Bs, lane, w);

  const int wy = w >> 1, wx = w & 1, l15 = lane & 15, quad = lane >> 4;
#pragma unroll
  for (int mi = 0; mi < 4; ++mi) {
    int rowb = m0 + wy * 64 + mi * 16 + quad * 4;
#pragma unroll
    for (int ni = 0; ni < 4; ++ni) {
      int col = n0 + wx * 64 + ni * 16 + l15;
      float bv = bias[col];
#pragma unroll
      for (int r = 0; r < 4; ++r)
        out[(size_t)(rowb + r) * NXq + col] = acc[mi][ni][r] + bv;
    }
  }
}

// ---------------------------------------------------------------------------
// launch
// ---------------------------------------------------------------------------
extern "C" void kernel_launch(void* const* d_in, const int* in_sizes, int n_in,
                              void* d_out, int out_size, void* d_ws, size_t ws_size,
                              hipStream_t stream) {
  const float* hidden   = (const float*)d_in[0];
  const float* c_attn_w = (const float*)d_in[1];
  const float* c_attn_b = (const float*)d_in[2];
  const float* c_proj_w = (const float*)d_in[3];
  const float* c_proj_b = (const float*)d_in[4];
  float* out = (float*)d_out;

  char* ws = (char*)d_ws;
  const size_t szX   = (size_t)8192 * 1024 * 2;
  const size_t szW1  = (size_t)3072 * 1024 * 2;
  const size_t szW2  = (size_t)1024 * 1024 * 2;
  const size_t szQKV = (size_t)Bq * NHq * Sq * HDq * 2;
  bf16_t* Xb  = (bf16_t*)(ws);
  bf16_t* Wt1 = (bf16_t*)(ws + szX);
  bf16_t* Wt2 = (bf16_t*)(ws + szX + szW1);
  bf16_t* qwp = (bf16_t*)(ws + szX + szW1 + szW2);
  bf16_t* kwp = (bf16_t*)(ws + szX + szW1 + szW2 + szQKV);
  bf16_t* vtp = (bf16_t*)(ws + szX + szW1 + szW2 + 2 * szQKV);
  bf16_t* awp = (bf16_t*)(ws + szX + szW1 + szW2 + 3 * szQKV);
  if (ws_size < szX + szW1 + szW2 + 4 * szQKV) return;

  cvt_bf16<<<dim3((8192 * 1024) / (256 * 4)), dim3(256), 0, stream>>>(
      hidden, Xb, 8192 * 1024);
  transpose_cvt<<<dim3(3072 / 32, 1024 / 32), dim3(32, 8), 0, stream>>>(
      c_attn_w, Wt1, 1024, 3072);
  transpose_cvt<<<dim3(1024 / 32, 1024 / 32), dim3(32, 8), 0, stream>>>(
      c_proj_w, Wt2, 1024, 1024);
  gemm_qkv<<<dim3(3072 / 128, 8192 / 128), dim3(256), 0, stream>>>(
      Xb, Wt1, c_attn_b, qwp, kwp, vtp);
  attn_fwd<<<dim3(1024), dim3(256), 0, stream>>>(qwp, kwp, vtp, awp);
  gemm_proj<<<dim3(1024 / 128, 8192 / 128), dim3(256), 0, stream>>>(
      awp, Wt2, c_proj_b, out);
}